// Round 2
// baseline (79.028 us; speedup 1.0000x reference)
//
#include <hip/hip_runtime.h>
#include <math.h>

// Problem constants (fixed by the reference)
#define B_ 512
#define K_ 1024
#define D_ 256
#define EPS_ 1e-6f

// Tiling: BM x BN output tile per block, BK K-chunk
#define BM 64
#define BN 32
#define BK 32
#define XLD (BM + 4)   // 68: row stride 272B -> 16B-aligned float4 reads, <=2-way bank conflict (free)
#define PLD (BN + 4)   // 36: row stride 144B -> 8B-aligned float2 reads

__global__ __launch_bounds__(256) void hyp_mlr_kernel(
    const float* __restrict__ x,   // [B, D]
    const float* __restrict__ p,   // [K, D]
    const float* __restrict__ a,   // [K, D]
    float* __restrict__ out)       // [B, K]
{
    // Double-buffered LDS: one __syncthreads per K-chunk, staging loads for
    // chunk k+1 issued before the compute loop on chunk k (latency hidden).
    __shared__ __align__(16) float Xs[2][BK][XLD];  // transposed: Xs[buf][d][b]
    __shared__ __align__(16) float Ps[2][BK][PLD];  // transposed: Ps[buf][d][k]
    __shared__ __align__(16) float As[2][BK][PLD];

    const int t  = threadIdx.x;
    const int tx = t & 15;    // k-dim: 2 cols each
    const int ty = t >> 4;    // b-dim: 4 rows each
    const int k0 = blockIdx.x * BN;
    const int b0 = blockIdx.y * BM;

    // staging-load mapping: one float4 per (row, 4-col chunk)
    const int lrow = t >> 3;        // 0..31
    const int lcol = (t & 7) * 4;   // 0,4,...,28

    const float* xg0 = &x[(b0 + lrow)      * D_ + lcol];
    const float* xg1 = &x[(b0 + lrow + 32) * D_ + lcol];
    const float* pg  = &p[(k0 + lrow)      * D_ + lcol];
    const float* ag  = &a[(k0 + lrow)      * D_ + lcol];

    float dotp[4][2] = {{0.f,0.f},{0.f,0.f},{0.f,0.f},{0.f,0.f}};
    float dota[4][2] = {{0.f,0.f},{0.f,0.f},{0.f,0.f},{0.f,0.f}};
    float x2a[4] = {0.f,0.f,0.f,0.f};
    float p2a[2] = {0.f,0.f};
    float a2a[2] = {0.f,0.f};
    float paa[2] = {0.f,0.f};

    // ---- prologue: load chunk 0 into buffer 0 ----
    {
        float4 v0 = *(const float4*)&xg0[0];
        float4 v1 = *(const float4*)&xg1[0];
        float4 vp = *(const float4*)&pg[0];
        float4 va = *(const float4*)&ag[0];
        Xs[0][lcol+0][lrow] = v0.x; Xs[0][lcol+1][lrow] = v0.y;
        Xs[0][lcol+2][lrow] = v0.z; Xs[0][lcol+3][lrow] = v0.w;
        Xs[0][lcol+0][lrow+32] = v1.x; Xs[0][lcol+1][lrow+32] = v1.y;
        Xs[0][lcol+2][lrow+32] = v1.z; Xs[0][lcol+3][lrow+32] = v1.w;
        Ps[0][lcol+0][lrow] = vp.x; Ps[0][lcol+1][lrow] = vp.y;
        Ps[0][lcol+2][lrow] = vp.z; Ps[0][lcol+3][lrow] = vp.w;
        As[0][lcol+0][lrow] = va.x; As[0][lcol+1][lrow] = va.y;
        As[0][lcol+2][lrow] = va.z; As[0][lcol+3][lrow] = va.w;
    }
    __syncthreads();

    int cur = 0;
    for (int kk = 0; kk < D_; kk += BK) {
        // ---- prefetch next chunk into registers (global latency overlaps j-loop) ----
        float4 nv0, nv1, nvp, nva;
        const bool has_next = (kk + BK) < D_;
        if (has_next) {
            const int off = kk + BK;
            nv0 = *(const float4*)&xg0[off];
            nv1 = *(const float4*)&xg1[off];
            nvp = *(const float4*)&pg[off];
            nva = *(const float4*)&ag[off];
        }

        // ---- compute on buffer `cur` ----
#pragma unroll 8
        for (int j = 0; j < BK; ++j) {
            float4 xv = *(const float4*)&Xs[cur][j][ty * 4];
            float2 pv = *(const float2*)&Ps[cur][j][tx * 2];
            float2 av = *(const float2*)&As[cur][j][tx * 2];
            float xr[4] = {xv.x, xv.y, xv.z, xv.w};
            float pr[2] = {pv.x, pv.y};
            float ar[2] = {av.x, av.y};
#pragma unroll
            for (int i = 0; i < 4; ++i) {
                x2a[i] = fmaf(xr[i], xr[i], x2a[i]);
#pragma unroll
                for (int c = 0; c < 2; ++c) {
                    dotp[i][c] = fmaf(xr[i], pr[c], dotp[i][c]);
                    dota[i][c] = fmaf(xr[i], ar[c], dota[i][c]);
                }
            }
#pragma unroll
            for (int c = 0; c < 2; ++c) {
                p2a[c] = fmaf(pr[c], pr[c], p2a[c]);
                a2a[c] = fmaf(ar[c], ar[c], a2a[c]);
                paa[c] = fmaf(pr[c], ar[c], paa[c]);
            }
        }

        // ---- write prefetched regs into the idle buffer, single barrier ----
        if (has_next) {
            const int nxt = cur ^ 1;
            Xs[nxt][lcol+0][lrow] = nv0.x; Xs[nxt][lcol+1][lrow] = nv0.y;
            Xs[nxt][lcol+2][lrow] = nv0.z; Xs[nxt][lcol+3][lrow] = nv0.w;
            Xs[nxt][lcol+0][lrow+32] = nv1.x; Xs[nxt][lcol+1][lrow+32] = nv1.y;
            Xs[nxt][lcol+2][lrow+32] = nv1.z; Xs[nxt][lcol+3][lrow+32] = nv1.w;
            Ps[nxt][lcol+0][lrow] = nvp.x; Ps[nxt][lcol+1][lrow] = nvp.y;
            Ps[nxt][lcol+2][lrow] = nvp.z; Ps[nxt][lcol+3][lrow] = nvp.w;
            As[nxt][lcol+0][lrow] = nva.x; As[nxt][lcol+1][lrow] = nva.y;
            As[nxt][lcol+2][lrow] = nva.z; As[nxt][lcol+3][lrow] = nva.w;
            __syncthreads();
            cur = nxt;
        }
    }

    // Epilogue: Ganea hyperbolic MLR logit from the 6 scalars.
    //   alpha = 1 - 2 dot + x2 ; beta = 1 - p2 ; gamma = 1 - 2 dot + p2*x2 + EPS
    //   z2 = (alpha^2 p2 - 2 alpha beta dot + beta^2 x2) / gamma^2
    //   za = beta (beta*xa - alpha*pa) / gamma
    //   na = beta*sqrt(a2); lam = 2/(beta+EPS)
    //   logit = lam * na * asinh(2 za / ((1 - z2) na + EPS))
#pragma unroll
    for (int i = 0; i < 4; ++i) {
        const int b = b0 + ty * 4 + i;
        const float x2 = x2a[i];
        float res[2];
#pragma unroll
        for (int c = 0; c < 2; ++c) {
            const float p2 = p2a[c];
            const float a2 = a2a[c];
            const float pa = paa[c];
            const float dt = dotp[i][c];
            const float xa = dota[i][c];

            const float beta  = 1.0f - p2;
            const float alpha = 1.0f + x2 - 2.0f * dt;
            const float den   = 1.0f - 2.0f * dt + p2 * x2;
            const float rg    = 1.0f / (den + EPS_);
            const float z2    = (alpha * alpha * p2 - 2.0f * alpha * beta * dt
                                 + beta * beta * x2) * rg * rg;
            const float za    = beta * (beta * xa - alpha * pa) * rg;
            const float na    = beta * sqrtf(a2);
            const float lam   = 2.0f / (beta + EPS_);
            const float arg   = 2.0f * za / ((1.0f - z2) * na + EPS_);
            res[c] = lam * na * asinhf(arg);
        }
        *(float2*)&out[b * K_ + k0 + tx * 2] = make_float2(res[0], res[1]);
    }
}

extern "C" void kernel_launch(void* const* d_in, const int* in_sizes, int n_in,
                              void* d_out, int out_size, void* d_ws, size_t ws_size,
                              hipStream_t stream) {
    const float* x = (const float*)d_in[0];  // [512, 256]
    const float* p = (const float*)d_in[1];  // [1024, 256]
    const float* a = (const float*)d_in[2];  // [1024, 256]
    float* out = (float*)d_out;              // [512, 1024]

    dim3 grid(K_ / BN, B_ / BM);   // (32, 8) = 256 blocks, 1 per CU
    dim3 block(256);
    hyp_mlr_kernel<<<grid, block, 0, stream>>>(x, p, a, out);
}

// Round 3
// 71.954 us; speedup vs baseline: 1.0983x; 1.0983x over previous
//
#include <hip/hip_runtime.h>
#include <math.h>

// Problem constants (fixed by the reference)
#define B_ 512
#define K_ 1024
#define D_ 256
#define EPS_ 1e-6f

// Tiling: 64(b) x 32(k) output tile per block; BK=32 staged per chunk.
// 1024 threads = 4 split-D groups x 256 compute slots (16 k-cols x 16 b-rows,
// micro-tile 4b x 2k per slot). Grid 256 blocks -> 16 waves/CU = 4 waves/SIMD.
#define BM 64
#define BN 32
#define BK 32
#define NG 4            // split-D groups
#define JG (BK / NG)    // 8 j-steps per group per chunk
#define XLD (BM + 4)    // 68: 16B-aligned float4 rows, odd bank-quad stride
#define PLD (BN + 4)    // 36: 8B-aligned float2 rows

__global__ __launch_bounds__(1024) void hyp_mlr_kernel(
    const float* __restrict__ x,   // [B, D]
    const float* __restrict__ p,   // [K, D]
    const float* __restrict__ a,   // [K, D]
    float* __restrict__ out)       // [B, K]
{
    __shared__ __align__(16) float Xs[2][BK][XLD];   // transposed: Xs[buf][d][b]
    __shared__ __align__(16) float Ps[2][BK][PLD];   // transposed: Ps[buf][d][k]
    __shared__ __align__(16) float As[2][BK][PLD];
    __shared__ float Red[256][27];                   // split-D reduction (27: odd stride, conflict-free)

    const int t  = threadIdx.x;
    const int u  = t & 255;    // compute slot
    const int g  = t >> 8;     // split-D group 0..3
    const int tx = u & 15;     // k: 2 cols
    const int ty = u >> 4;     // b: 4 rows
    const int k0 = blockIdx.x * BN;
    const int b0 = blockIdx.y * BM;

    // ---- staging map: exactly one float4 per thread per chunk ----
    // t<512 -> X tile (64 rows x 8 f4); t in [512,768) -> P (32x8); t>=768 -> A (32x8)
    int lrow, lcol;
    const float* gsrc;
    if (t < 512)      { lrow = t >> 3;          lcol = (t & 7) * 4; gsrc = &x[(b0 + lrow) * D_ + lcol]; }
    else if (t < 768) { const int q = t - 512;  lrow = q >> 3; lcol = (q & 7) * 4; gsrc = &p[(k0 + lrow) * D_ + lcol]; }
    else              { const int q = t - 768;  lrow = q >> 3; lcol = (q & 7) * 4; gsrc = &a[(k0 + lrow) * D_ + lcol]; }

    auto stage = [&](int buf, float4 v) {
        if (t < 512) {
            Xs[buf][lcol+0][lrow] = v.x; Xs[buf][lcol+1][lrow] = v.y;
            Xs[buf][lcol+2][lrow] = v.z; Xs[buf][lcol+3][lrow] = v.w;
        } else if (t < 768) {
            Ps[buf][lcol+0][lrow] = v.x; Ps[buf][lcol+1][lrow] = v.y;
            Ps[buf][lcol+2][lrow] = v.z; Ps[buf][lcol+3][lrow] = v.w;
        } else {
            As[buf][lcol+0][lrow] = v.x; As[buf][lcol+1][lrow] = v.y;
            As[buf][lcol+2][lrow] = v.z; As[buf][lcol+3][lrow] = v.w;
        }
    };

    float dotp[4][2] = {{0.f,0.f},{0.f,0.f},{0.f,0.f},{0.f,0.f}};
    float dota[4][2] = {{0.f,0.f},{0.f,0.f},{0.f,0.f},{0.f,0.f}};
    float x2a[4] = {0.f,0.f,0.f,0.f};
    float p2a[2] = {0.f,0.f};
    float a2a[2] = {0.f,0.f};
    float paa[2] = {0.f,0.f};

    // ---- prologue ----
    stage(0, *(const float4*)gsrc);
    __syncthreads();

    int cur = 0;
    for (int kk = 0; kk < D_; kk += BK) {
        float4 nv;
        const bool hn = (kk + BK) < D_;
        if (hn) nv = *(const float4*)(gsrc + kk + BK);

        // ---- compute: group g handles d = g*8 .. g*8+7 of this chunk ----
#pragma unroll
        for (int j = 0; j < JG; ++j) {
            const int d = g * JG + j;
            float4 xv = *(const float4*)&Xs[cur][d][ty * 4];
            float2 pv = *(const float2*)&Ps[cur][d][tx * 2];
            float2 av = *(const float2*)&As[cur][d][tx * 2];
            float xr[4] = {xv.x, xv.y, xv.z, xv.w};
            float pr[2] = {pv.x, pv.y};
            float ar[2] = {av.x, av.y};
#pragma unroll
            for (int i = 0; i < 4; ++i) {
                x2a[i] = fmaf(xr[i], xr[i], x2a[i]);
#pragma unroll
                for (int c = 0; c < 2; ++c) {
                    dotp[i][c] = fmaf(xr[i], pr[c], dotp[i][c]);
                    dota[i][c] = fmaf(xr[i], ar[c], dota[i][c]);
                }
            }
#pragma unroll
            for (int c = 0; c < 2; ++c) {
                p2a[c] = fmaf(pr[c], pr[c], p2a[c]);
                a2a[c] = fmaf(ar[c], ar[c], a2a[c]);
                paa[c] = fmaf(pr[c], ar[c], paa[c]);
            }
        }

        if (hn) {
            stage(cur ^ 1, nv);
            __syncthreads();
            cur ^= 1;
        }
    }

    // ---- split-D reduction: pack 26 partials, combine groups via LDS ----
    float pay[26];
#pragma unroll
    for (int i = 0; i < 4; ++i) {
        pay[i * 2 + 0] = dotp[i][0]; pay[i * 2 + 1] = dotp[i][1];
        pay[8 + i * 2 + 0] = dota[i][0]; pay[8 + i * 2 + 1] = dota[i][1];
        pay[16 + i] = x2a[i];
    }
    pay[20] = p2a[0]; pay[21] = p2a[1];
    pay[22] = a2a[0]; pay[23] = a2a[1];
    pay[24] = paa[0]; pay[25] = paa[1];

    __syncthreads();
    if (g == 1) {
#pragma unroll
        for (int j = 0; j < 26; ++j) Red[u][j] = pay[j];
    }
    __syncthreads();
    if (g == 2) {
#pragma unroll
        for (int j = 0; j < 26; ++j) Red[u][j] += pay[j];
    }
    __syncthreads();
    if (g == 3) {
#pragma unroll
        for (int j = 0; j < 26; ++j) Red[u][j] += pay[j];
    }
    __syncthreads();

    if (g == 0) {
#pragma unroll
        for (int j = 0; j < 26; ++j) pay[j] += Red[u][j];

        // Epilogue: Ganea hyperbolic MLR logit from the 6 scalars.
        //   alpha = 1 - 2 dot + x2 ; beta = 1 - p2 ; gamma = 1 - 2 dot + p2*x2 + EPS
        //   z2 = (alpha^2 p2 - 2 alpha beta dot + beta^2 x2) / gamma^2
        //   za = beta (beta*xa - alpha*pa) / gamma
        //   na = beta*sqrt(a2); lam = 2/(beta+EPS)
        //   logit = lam * na * asinh(2 za / ((1 - z2) na + EPS))
#pragma unroll
        for (int i = 0; i < 4; ++i) {
            const int b = b0 + ty * 4 + i;
            const float x2 = pay[16 + i];
            float res[2];
#pragma unroll
            for (int c = 0; c < 2; ++c) {
                const float p2 = pay[20 + c];
                const float a2 = pay[22 + c];
                const float pa = pay[24 + c];
                const float dt = pay[i * 2 + c];
                const float xa = pay[8 + i * 2 + c];

                const float beta  = 1.0f - p2;
                const float alpha = 1.0f + x2 - 2.0f * dt;
                const float den   = 1.0f - 2.0f * dt + p2 * x2;
                const float rg    = 1.0f / (den + EPS_);
                const float z2    = (alpha * alpha * p2 - 2.0f * alpha * beta * dt
                                     + beta * beta * x2) * rg * rg;
                const float za    = beta * (beta * xa - alpha * pa) * rg;
                const float na    = beta * sqrtf(a2);
                const float lam   = 2.0f / (beta + EPS_);
                const float arg   = 2.0f * za / ((1.0f - z2) * na + EPS_);
                res[c] = lam * na * asinhf(arg);
            }
            *(float2*)&out[b * K_ + k0 + tx * 2] = make_float2(res[0], res[1]);
        }
    }
}

extern "C" void kernel_launch(void* const* d_in, const int* in_sizes, int n_in,
                              void* d_out, int out_size, void* d_ws, size_t ws_size,
                              hipStream_t stream) {
    const float* x = (const float*)d_in[0];  // [512, 256]
    const float* p = (const float*)d_in[1];  // [1024, 256]
    const float* a = (const float*)d_in[2];  // [1024, 256]
    float* out = (float*)d_out;              // [512, 1024]

    dim3 grid(K_ / BN, B_ / BM);   // (32, 8) = 256 blocks
    dim3 block(1024);              // 16 waves -> 4 waves/SIMD at 1 block/CU
    hyp_mlr_kernel<<<grid, block, 0, stream>>>(x, p, a, out);
}